// Round 9
// baseline (6232.429 us; speedup 1.0000x reference)
//
#include <hip/hip_runtime.h>
#include <hip/hip_bf16.h>
#include <stdint.h>

// Problem dims
#define BB 64
#define SS 512
#define EE 256
#define HH 1024
#define VV 128

typedef __attribute__((ext_vector_type(8))) short short8;
typedef __attribute__((ext_vector_type(4))) float floatx4;

// ---- LDS layout (dynamic, one blob) ----
// HA staging removed: A-fragments now gathered straight into registers.
#define LDS_UFRAG 0                 // 3 gates * 32 ktiles * 64 lanes * 16B = 98304
#define LDS_REDA  98304             // 8 slots * 64 lanes * 16B fp32 = 8192  (phase A r,z)
#define LDS_REDB  106496            // 4 slots * 64 lanes * 16B fp32 = 4096  (phase B h)
#define LDS_TOK   110592            // 16 * 512 u8 tokens = 8192
#define LDS_HOWN  118784            // 16*16 fp32 own-h slice = 1024
#define LDS_ZBUF  119808            // 16*16 fp32 z slice = 1024
#define LDS_XFER  120832            // 16*16 fp32 transfer tile (wave0 rh) = 1024
#define LDS_TOTAL 121856            // 2x won't fit in 160KB -> 1 block/CU preserved

// ---- workspace layout (bytes) ----
#define WS_TABLE  0                  // 128*3*1024 fp32 = 1572864
#define WS_RH     1572864            // 64*1024 bf16 = 131072
#define WS_FLAGS  1703936            // flagsA[256], flagsB[256] ints = 2048 (memset region)
#define WS_OUTS   2097152            // 512*64*1024 bf16 = 67108864

__device__ __forceinline__ unsigned short f2bf(float f) {
  union { float f; unsigned int i; } x; x.f = f;
  unsigned int r = x.i + 0x7fffu + ((x.i >> 16) & 1u);
  return (unsigned short)(r >> 16);
}
__device__ __forceinline__ unsigned long long pack4bf(float a, float b, float c, float d) {
  unsigned int lo = ((unsigned int)f2bf(b) << 16) | f2bf(a);
  unsigned int hi = ((unsigned int)f2bf(d) << 16) | f2bf(c);
  return ((unsigned long long)hi << 32) | lo;
}
// sc1 store: lands at the cross-XCD coherence point, never dirties L2.
__device__ __forceinline__ void st_agent_b64(unsigned long long* p, unsigned long long v) {
  __hip_atomic_store(p, v, __ATOMIC_RELAXED, __HIP_MEMORY_SCOPE_AGENT);
}

// table[v][g][j] = sum_e emb[v][e] * W_g[j][e] + 2*b_g[j]   (fp32 in, fp32 out)
__global__ void __launch_bounds__(256)
table_kernel(const float* __restrict__ emb,
             const float* __restrict__ Wr, const float* __restrict__ br,
             const float* __restrict__ Wz, const float* __restrict__ bz,
             const float* __restrict__ Wh, const float* __restrict__ bh,
             float* __restrict__ table) {
  int id = blockIdx.x * 256 + threadIdx.x;          // 128*3*1024 = 393216 exact
  int v = id / 3072;
  int rem = id - v * 3072;
  int g = rem >> 10;
  int j = rem & 1023;
  const float* W  = (g == 0) ? Wr : (g == 1) ? Wz : Wh;
  const float* bb = (g == 0) ? br : (g == 1) ? bz : bh;
  const float4* ev = (const float4*)(emb + (size_t)v * EE);
  const float4* wv = (const float4*)(W + (size_t)j * EE);
  float acc = 2.f * bb[j];                          // faithful: bias added twice
  for (int e = 0; e < EE / 4; ++e) {
    float4 a = ev[e], b4 = wv[e];
    acc += a.x * b4.x + a.y * b4.y + a.z * b4.z + a.w * b4.w;
  }
  table[id] = acc;
}

// Coalesced bypass poll: 16 lanes read the group's 64 flags as dwordx4 sc0 sc1;
// wave returns when all 64 flags >= tgt. Lanes >=16 duplicate lane&15's address
// (coalescer broadcasts). Flags are written by independent per-WG relaxed
// agent stores (ordered behind data by the producer's vmcnt(0) drain).
__device__ __forceinline__ void poll_flags(const int* flags, int tgt, int lane) {
  const char* fp = (const char*)flags + (lane & 15) * 16;
  for (;;) {
    uint4 f;
    asm volatile("global_load_dwordx4 %0, %1, off sc0 sc1\n\t"
                 "s_waitcnt vmcnt(0)"
                 : "=v"(f) : "v"(fp) : "memory");
    bool ok = ((int)f.x >= tgt) & ((int)f.y >= tgt) &
              ((int)f.z >= tgt) & ((int)f.w >= tgt);
    if (__all(ok)) break;
    __builtin_amdgcn_s_sleep(1);
  }
}

// Persistent GRU. 256 blocks x 256 threads, 1 block/CU (LDS-forced).
// blockIdx: group = >>6 (batch slice of 16), col = &63 (16 output columns).
// Per step: exactly 2 barriers (B1 after phase-A red writes, B2 after phase-B).
// All cross-wave LDS hazards ordered by {B1,B2} or by the producer-flag chain
// (h_own: wave2 writes before flagB, wave0 reads after its flagsB poll).
__global__ void __launch_bounds__(256, 1)
gru_kernel(const int* __restrict__ x,
           const float* __restrict__ Ur, const float* __restrict__ Uz,
           const float* __restrict__ Uh,
           const float* __restrict__ table,
           unsigned short* __restrict__ outs,     // [S][B][H] bf16 (sc1-written, cached reads)
           unsigned short* __restrict__ rhbuf,    // [B][H] bf16 (sc1-written, bypass reads)
           float* __restrict__ hlast,             // [B][H] fp32 -> d_out tail
           int* __restrict__ flagsA, int* __restrict__ flagsB) {
  extern __shared__ char smem[];
  const int tid = threadIdx.x;
  const int lane = tid & 63;
  const int w = tid >> 6;            // wave 0..3, owns K-slice [w*256, w*256+256)
  const int wg = blockIdx.x;
  const int group = wg >> 6;
  const int col = wg & 63;
  const int j0 = col << 4;

  float* redA  = (float*)(smem + LDS_REDA);
  float* redB  = (float*)(smem + LDS_REDB);
  float* h_own = (float*)(smem + LDS_HOWN);
  float* zbuf  = (float*)(smem + LDS_ZBUF);
  float* xfer  = (float*)(smem + LDS_XFER);
  const unsigned char* toks = (const unsigned char*)(smem + LDS_TOK);
  const int* myflagsA = flagsA + group * 64;
  const int* myflagsB = flagsB + group * 64;

  // ---- init: U (fp32) -> LDS bf16 in MFMA B-frag order; tokens; h_own = 0 ----
  {
    const float* Us[3] = {Ur, Uz, Uh};
    for (int c = w * 24; c < w * 24 + 24; ++c) {     // 96 (gate,ktile) chunks / 4 waves
      int g = c >> 5, kt = c & 31;
      // B-frag: lane holds U[j0+(lane&15)][kt*32 + (lane>>4)*8 + 0..7]
      const float* src = Us[g] + (size_t)(j0 + (lane & 15)) * HH + kt * 32 + (lane >> 4) * 8;
      float4 f0 = ((const float4*)src)[0];
      float4 f1 = ((const float4*)src)[1];
      short8 frag;
      frag[0] = (short)f2bf(f0.x); frag[1] = (short)f2bf(f0.y);
      frag[2] = (short)f2bf(f0.z); frag[3] = (short)f2bf(f0.w);
      frag[4] = (short)f2bf(f1.x); frag[5] = (short)f2bf(f1.y);
      frag[6] = (short)f2bf(f1.z); frag[7] = (short)f2bf(f1.w);
      *(short8*)(smem + ((g * 32 + kt) * 64 + lane) * 16) = frag;
    }
    for (int i = tid; i < 16 * SS; i += 256) {
      int b = i >> 9, t = i & 511;
      smem[LDS_TOK + i] = (char)x[(size_t)(group * 16 + b) * SS + t];
    }
    ((float*)(smem + LDS_HOWN))[tid] = 0.f;
  }
  __syncthreads();

  for (int t = 0; t < SS; ++t) {
    // ---- prefetch this step's x-projection rows (tokens known ahead of time;
    // pulls the table L2 read off the post-MFMA critical path). gate = w.
    float xpre[4];
    if (w < 3) {
      const int j = lane & 15;
      const float* tb = table + w * 1024 + j0 + j;
#pragma unroll
      for (int i = 0; i < 4; ++i) {
        int b = (lane >> 4) * 4 + i;
        int tok = toks[b * SS + t];
        xpre[i] = tb[tok * 3072];
      }
    }

    // ================= phase A : r, z =================
    // Direct register gather of this wave's A-frags from outs[t-1]:
    // lane holds h[group*16+(lane&15)][kt*32 + (lane>>4)*8 + 0..7], kt = w*8+i.
    // Plain cached loads: lines first-touched after the flag (fresh address
    // per t), written once via sc1 -> never stale in L1/L2.
    short8 ha[8];
    if (t > 0) {
      poll_flags(myflagsB, t, lane);                 // all waves poll
      const unsigned short* hb = outs + ((size_t)(t - 1) * BB + group * 16 + (lane & 15)) * HH
                               + w * 256 + (lane >> 4) * 8;
#pragma unroll
      for (int i = 0; i < 8; ++i)
        ha[i] = *(const short8*)(hb + i * 32);
    } else {
      short8 z8 = {0, 0, 0, 0, 0, 0, 0, 0};
#pragma unroll
      for (int i = 0; i < 8; ++i) ha[i] = z8;
    }

    floatx4 accr = {0,0,0,0}, accz = {0,0,0,0};
#pragma unroll
    for (int ktl = 0; ktl < 8; ++ktl) {
      const int kt = w * 8 + ktl;
      short8 br_ = *(const short8*)(smem + ((0 * 32 + kt) * 64 + lane) * 16);
      short8 bz_ = *(const short8*)(smem + ((1 * 32 + kt) * 64 + lane) * 16);
      accr = __builtin_amdgcn_mfma_f32_16x16x32_bf16(ha[ktl], br_, accr, 0, 0, 0);
      accz = __builtin_amdgcn_mfma_f32_16x16x32_bf16(ha[ktl], bz_, accz, 0, 0, 0);
    }
    *(floatx4*)(redA + ((w * 2 + 0) * 64 + lane) * 4) = accr;
    *(floatx4*)(redA + ((w * 2 + 1) * 64 + lane) * 4) = accz;
    __syncthreads();                                  // B1

    if (w == 0) {           // finalize r; pack r*h row-contiguous; sc1-store to handoff
      floatx4 s = {0,0,0,0};
      for (int ww = 0; ww < 4; ++ww) s += *(const floatx4*)(redA + ((ww * 2) * 64 + lane) * 4);
      const int j = lane & 15;
#pragma unroll
      for (int i = 0; i < 4; ++i) {
        int b = (lane >> 4) * 4 + i;              // C-layout: row=(lane>>4)*4+reg, col=lane&15
        float r = 1.f / (1.f + __expf(-(s[i] + xpre[i])));
        xfer[b * 16 + j] = r * h_own[b * 16 + j];
      }
      asm volatile("s_waitcnt lgkmcnt(0)" ::: "memory");   // cross-lane LDS RAW (same wave)
      int row = lane >> 2, c0 = (lane & 3) * 4;
      unsigned long long pk = pack4bf(xfer[row * 16 + c0 + 0], xfer[row * 16 + c0 + 1],
                                      xfer[row * 16 + c0 + 2], xfer[row * 16 + c0 + 3]);
      st_agent_b64((unsigned long long*)(rhbuf + (size_t)(group * 16 + row) * HH + j0 + c0), pk);
      // release: vmcnt(0) drains wave0's sc1 stores, then relaxed sc1 flag
      asm volatile("s_waitcnt vmcnt(0)" ::: "memory");
      if (lane == 0)
        __hip_atomic_store(flagsA + wg, t + 1, __ATOMIC_RELAXED, __HIP_MEMORY_SCOPE_AGENT);
    } else if (w == 1) {    // finalize z, keep in LDS
      floatx4 s = {0,0,0,0};
      for (int ww = 0; ww < 4; ++ww) s += *(const floatx4*)(redA + ((ww * 2 + 1) * 64 + lane) * 4);
      const int j = lane & 15;
#pragma unroll
      for (int i = 0; i < 4; ++i) {
        int b = (lane >> 4) * 4 + i;
        zbuf[b * 16 + j] = 1.f / (1.f + __expf(-(s[i] + xpre[i])));
      }
    }

    // ================= phase B : h_tilde, h_new =================
    poll_flags(myflagsA, t + 1, lane);               // all waves poll (overlaps w0 finalize)
    // Direct register gather of rh frags (addresses reused every step -> LLC
    // bypass sc0 sc1). Same frag layout as phase A.
    short8 rha0, rha1, rha2, rha3, rha4, rha5, rha6, rha7;
    {
      const char* rb = (const char*)(rhbuf + (size_t)(group * 16 + (lane & 15)) * HH
                                     + w * 256 + (lane >> 4) * 8);
      asm volatile(
        "global_load_dwordx4 %0, %8, off sc0 sc1\n\t"
        "global_load_dwordx4 %1, %8, off offset:64 sc0 sc1\n\t"
        "global_load_dwordx4 %2, %8, off offset:128 sc0 sc1\n\t"
        "global_load_dwordx4 %3, %8, off offset:192 sc0 sc1\n\t"
        "global_load_dwordx4 %4, %8, off offset:256 sc0 sc1\n\t"
        "global_load_dwordx4 %5, %8, off offset:320 sc0 sc1\n\t"
        "global_load_dwordx4 %6, %8, off offset:384 sc0 sc1\n\t"
        "global_load_dwordx4 %7, %8, off offset:448 sc0 sc1\n\t"
        "s_waitcnt vmcnt(0)"
        : "=v"(rha0), "=v"(rha1), "=v"(rha2), "=v"(rha3),
          "=v"(rha4), "=v"(rha5), "=v"(rha6), "=v"(rha7)
        : "v"(rb)
        : "memory");
    }

    floatx4 acch = {0,0,0,0};
    {
      short8 rha[8] = {rha0, rha1, rha2, rha3, rha4, rha5, rha6, rha7};
#pragma unroll
      for (int ktl = 0; ktl < 8; ++ktl) {
        const int kt = w * 8 + ktl;
        short8 bh_ = *(const short8*)(smem + ((2 * 32 + kt) * 64 + lane) * 16);
        acch = __builtin_amdgcn_mfma_f32_16x16x32_bf16(rha[ktl], bh_, acch, 0, 0, 0);
      }
    }
    *(floatx4*)(redB + (w * 64 + lane) * 4) = acch;
    __syncthreads();                                  // B2

    if (w == 2) {
      floatx4 s = {0,0,0,0};
      for (int ww = 0; ww < 4; ++ww) s += *(const floatx4*)(redB + (ww * 64 + lane) * 4);
      const int j = lane & 15;
#pragma unroll
      for (int i = 0; i < 4; ++i) {
        int b = (lane >> 4) * 4 + i;
        float ht = tanhf(s[i] + xpre[i]);
        float z = zbuf[b * 16 + j];
        float hp = h_own[b * 16 + j];
        h_own[b * 16 + j] = (1.f - z) * ht + z * hp;  // fp32 master copy persists
      }
      asm volatile("s_waitcnt lgkmcnt(0)" ::: "memory");   // cross-lane LDS RAW (same wave)
      int row = lane >> 2, c0 = (lane & 3) * 4;
      float f0 = h_own[row * 16 + c0 + 0], f1 = h_own[row * 16 + c0 + 1];
      float f2 = h_own[row * 16 + c0 + 2], f3 = h_own[row * 16 + c0 + 3];
      st_agent_b64((unsigned long long*)(outs + (size_t)(t * BB + group * 16 + row) * HH + j0 + c0),
                   pack4bf(f0, f1, f2, f3));
      if (t == SS - 1) {
        float4 v4 = {f0, f1, f2, f3};
        *(float4*)(hlast + (size_t)(group * 16 + row) * HH + j0 + c0) = v4;  // fp32, plain
      }
      // release: vmcnt(0) drains wave2's sc1 outs stores, then relaxed sc1 flag
      asm volatile("s_waitcnt vmcnt(0)" ::: "memory");
      if (lane == 0)
        __hip_atomic_store(flagsB + wg, t + 1, __ATOMIC_RELAXED, __HIP_MEMORY_SCOPE_AGENT);
    }
    // no trailing sync: next step's flagsB poll + B1 cover all remaining hazards
  }
}

// logits[b][s][v] = outs[s][b][:] . Wfc[v][:] + b_fc[v]   (fp32 out)
__global__ void __launch_bounds__(256)
logits_kernel(const unsigned short* __restrict__ outs, const float* __restrict__ Wfc,
              const float* __restrict__ bfc, float* __restrict__ out) {
  const int lane = threadIdx.x & 63;
  const int mt = blockIdx.x * 4 + (threadIdx.x >> 6);  // M-tile 0..2047 (M = S*B = 32768)
  const size_t arow = (size_t)(mt * 16 + (lane & 15)) * HH + (lane >> 4) * 8;
  floatx4 zero = {0,0,0,0};
  floatx4 acc[8];
#pragma unroll
  for (int n = 0; n < 8; ++n) acc[n] = zero;
  for (int kt = 0; kt < 32; ++kt) {
    short8 a = *(const short8*)(outs + arow + kt * 32);
#pragma unroll
    for (int n = 0; n < 8; ++n) {
      const float* wsrc = Wfc + (size_t)(n * 16 + (lane & 15)) * HH + kt * 32 + (lane >> 4) * 8;
      float4 f0 = ((const float4*)wsrc)[0];
      float4 f1 = ((const float4*)wsrc)[1];
      short8 b;
      b[0] = (short)f2bf(f0.x); b[1] = (short)f2bf(f0.y);
      b[2] = (short)f2bf(f0.z); b[3] = (short)f2bf(f0.w);
      b[4] = (short)f2bf(f1.x); b[5] = (short)f2bf(f1.y);
      b[6] = (short)f2bf(f1.z); b[7] = (short)f2bf(f1.w);
      acc[n] = __builtin_amdgcn_mfma_f32_16x16x32_bf16(a, b, acc[n], 0, 0, 0);
    }
  }
#pragma unroll
  for (int n = 0; n < 8; ++n) {
    int v = n * 16 + (lane & 15);
    float bias = bfc[v];
#pragma unroll
    for (int i = 0; i < 4; ++i) {
      int m = mt * 16 + (lane >> 4) * 4 + i;
      int s = m >> 6, b = m & 63;
      out[((size_t)b * SS + s) * VV + v] = acc[n][i] + bias;
    }
  }
}

extern "C" void kernel_launch(void* const* d_in, const int* in_sizes, int n_in,
                              void* d_out, int out_size, void* d_ws, size_t ws_size,
                              hipStream_t stream) {
  const int*   x    = (const int*)d_in[0];
  const float* emb  = (const float*)d_in[1];
  const float* W_r  = (const float*)d_in[2];
  const float* U_r  = (const float*)d_in[3];
  const float* b_r  = (const float*)d_in[4];
  const float* W_z  = (const float*)d_in[5];
  const float* U_z  = (const float*)d_in[6];
  const float* b_z  = (const float*)d_in[7];
  const float* W_h  = (const float*)d_in[8];
  const float* U_h  = (const float*)d_in[9];
  const float* b_h  = (const float*)d_in[10];
  const float* W_fc = (const float*)d_in[11];
  const float* b_fc = (const float*)d_in[12];

  char* ws = (char*)d_ws;
  float*          table  = (float*)(ws + WS_TABLE);
  unsigned short* rhbuf  = (unsigned short*)(ws + WS_RH);
  int*            flagsA = (int*)(ws + WS_FLAGS);
  int*            flagsB = (int*)(ws + WS_FLAGS + 1024);
  unsigned short* outs   = (unsigned short*)(ws + WS_OUTS);
  float*          out    = (float*)d_out;
  float*          hlast  = out + (size_t)BB * SS * VV;   // output 1, fp32

  // flags must start at 0 every call (ws is re-poisoned to 0xAA)
  hipMemsetAsync(ws + WS_FLAGS, 0, 2048, stream);

  table_kernel<<<dim3((128 * 3 * 1024) / 256), dim3(256), 0, stream>>>(
      emb, W_r, b_r, W_z, b_z, W_h, b_h, table);

  hipFuncSetAttribute(reinterpret_cast<const void*>(gru_kernel),
                      hipFuncAttributeMaxDynamicSharedMemorySize, LDS_TOTAL);
  void* args[] = {(void*)&x, (void*)&U_r, (void*)&U_z, (void*)&U_h, (void*)&table,
                  (void*)&outs, (void*)&rhbuf, (void*)&hlast, (void*)&flagsA, (void*)&flagsB};
  hipError_t cerr = hipLaunchCooperativeKernel(reinterpret_cast<void*>(gru_kernel),
                                               dim3(256), dim3(256),
                                               args, (unsigned)LDS_TOTAL, stream);
  if (cerr != hipSuccess) {
    // Fallback: plain launch. grid.sync() is never used; 1-block/CU LDS
    // forcing makes all 256 blocks co-resident, which the flag protocol needs.
    // (R7 lesson: an unchecked cooperative-launch failure looks like a silent
    // no-op and poisons the output.)
    gru_kernel<<<dim3(256), dim3(256), LDS_TOTAL, stream>>>(
        x, U_r, U_z, U_h, table, outs, rhbuf, hlast, flagsA, flagsB);
  }

  logits_kernel<<<dim3(512), dim3(256), 0, stream>>>(outs, W_fc, b_fc, out);
}

// Round 10
// 3695.905 us; speedup vs baseline: 1.6863x; 1.6863x over previous
//
#include <hip/hip_runtime.h>
#include <hip/hip_bf16.h>
#include <stdint.h>

// Problem dims
#define BB 64
#define SS 512
#define EE 256
#define HH 1024
#define VV 128

// Decomposition: 8 groups x 32 blocks; block owns 32 H-cols x 8 batch rows.
// U_r, U_h in LDS (128KB); U_z in registers (16 short8/lane, one gate).
// Exchange protocol: R2/R8-proven LLC (sc1) scheme. XCD fast path NOT enabled
// this round — topology check runs but its result is sunk (verification only).
#define GROUPS 8
#define GBLK   32
#define GROWS  8

typedef __attribute__((ext_vector_type(8))) short short8;
typedef __attribute__((ext_vector_type(4))) float floatx4;

// ---- LDS layout ----
#define LDS_UF    0        // 2 gates(r,h) * 32 kt * 2 nt * 1024B = 131072
#define LDS_REDA  131072   // 16 slots * 64 lanes * 16B = 16384  (phase A: r,z x 2nt x 4w)
#define LDS_REDB  147456   // 8 slots * 64 lanes * 16B = 8192    (phase B: h x 2nt x 4w)
#define LDS_HOWN  155648   // 8x32 fp32 = 1024
#define LDS_ZBUF  156672   // 8x32 fp32 = 1024
#define LDS_XFER  157696   // 8x32 fp32 = 1024
#define LDS_ALLOC 158720   // >80KB -> 1 block/CU

// ---- workspace layout (bytes) ----
#define WS_TABLE  0                  // 128*3*1024 fp32 = 1572864
#define WS_RH     1572864            // 64*1024 bf16 = 131072
#define WS_FLAGS  1703936            // flagsA[256] | flagsB[256] | xccOf[256] | cnt (memset 4096)
#define WS_OUTS   2097152            // 512*64*1024 bf16

__device__ __forceinline__ unsigned short f2bf(float f) {
  union { float f; unsigned int i; } x; x.f = f;
  unsigned int r = x.i + 0x7fffu + ((x.i >> 16) & 1u);
  return (unsigned short)(r >> 16);
}
__device__ __forceinline__ unsigned long long pack4bf(float a, float b, float c, float d) {
  unsigned int lo = ((unsigned int)f2bf(b) << 16) | f2bf(a);
  unsigned int hi = ((unsigned int)f2bf(d) << 16) | f2bf(c);
  return ((unsigned long long)hi << 32) | lo;
}
// sc1 store: lands at the cross-XCD coherence point (LLC), never dirties L2.
__device__ __forceinline__ void st_agent_b64(unsigned long long* p, unsigned long long v) {
  __hip_atomic_store(p, v, __ATOMIC_RELAXED, __HIP_MEMORY_SCOPE_AGENT);
}

// table[v][g][j] = sum_e emb[v][e] * W_g[j][e] + 2*b_g[j]   (fp32 in, fp32 out)
__global__ void __launch_bounds__(256)
table_kernel(const float* __restrict__ emb,
             const float* __restrict__ Wr, const float* __restrict__ br,
             const float* __restrict__ Wz, const float* __restrict__ bz,
             const float* __restrict__ Wh, const float* __restrict__ bh,
             float* __restrict__ table) {
  int id = blockIdx.x * 256 + threadIdx.x;          // 128*3*1024 = 393216 exact
  int v = id / 3072;
  int rem = id - v * 3072;
  int g = rem >> 10;
  int j = rem & 1023;
  const float* W  = (g == 0) ? Wr : (g == 1) ? Wz : Wh;
  const float* bb = (g == 0) ? br : (g == 1) ? bz : bh;
  const float4* ev = (const float4*)(emb + (size_t)v * EE);
  const float4* wv = (const float4*)(W + (size_t)j * EE);
  float acc = 2.f * bb[j];                          // faithful: bias added twice
  for (int e = 0; e < EE / 4; ++e) {
    float4 a = ev[e], b4 = wv[e];
    acc += a.x * b4.x + a.y * b4.y + a.z * b4.z + a.w * b4.w;
  }
  table[id] = acc;
}

// Poll the group's 32 flags: lanes 0..7 read dwordx4 (4 flags each), others
// duplicate lane&7 (coalescer broadcasts). LLC bypass (sc0 sc1) + sleep.
__device__ __forceinline__ void poll32(const int* flags, int tgt, int lane) {
  const char* fp = (const char*)flags + (lane & 7) * 16;
  for (;;) {
    uint4 f;
    asm volatile("global_load_dwordx4 %0, %1, off sc0 sc1\n\t"
                 "s_waitcnt vmcnt(0)" : "=v"(f) : "v"(fp) : "memory");
    bool ok = ((int)f.x >= tgt) & ((int)f.y >= tgt) &
              ((int)f.z >= tgt) & ((int)f.w >= tgt);
    if (__all(ok)) break;
    __builtin_amdgcn_s_sleep(1);
  }
}

// Persistent GRU. 256 blocks x 256 threads, 1 block/CU (LDS-forced).
// group = wg & 7, slot = wg >> 3, j0 = slot*32. Wave w owns K-slice w*256..+256.
// 2 barriers/step (B1 after redA writes, B2 after redB writes); remaining
// cross-wave hazards ordered by the producer-flag chains (verified in R9).
__global__ void __launch_bounds__(256, 1)
gru_kernel(const int* __restrict__ x,
           const float* __restrict__ Ur, const float* __restrict__ Uz,
           const float* __restrict__ Uh,
           const float* __restrict__ table,
           unsigned short* __restrict__ outs,     // [S][B][H] bf16 (sc1-written, cached reads)
           unsigned short* __restrict__ rhbuf,    // [B][H] bf16 (sc1-written, bypass reads)
           float* __restrict__ hlast,             // [B][H] fp32 -> d_out tail
           int* __restrict__ flagsA, int* __restrict__ flagsB,
           int* __restrict__ xccOf, int* __restrict__ cnt) {
  extern __shared__ char smem[];
  const int tid = threadIdx.x;
  const int lane = tid & 63;
  const int w = tid >> 6;
  const int wg = blockIdx.x;
  const int group = wg & 7;
  const int slot = wg >> 3;
  const int j0 = slot << 5;          // 32 columns per block

  float* redA  = (float*)(smem + LDS_REDA);
  float* redB  = (float*)(smem + LDS_REDB);
  float* h_own = (float*)(smem + LDS_HOWN);
  float* zbuf  = (float*)(smem + LDS_ZBUF);
  float* xfer  = (float*)(smem + LDS_XFER);
  const int* myA = flagsA + group * GBLK;
  const int* myB = flagsB + group * GBLK;

  // ---- topology publish (result sunk this round; fast path comes next) ----
  unsigned xcc;
  asm volatile("s_getreg_b32 %0, hwreg(HW_REG_XCC_ID)" : "=s"(xcc));
  if (tid == 0) {
    __hip_atomic_store(xccOf + wg, (int)xcc + 1, __ATOMIC_RELAXED, __HIP_MEMORY_SCOPE_AGENT);
    asm volatile("s_waitcnt vmcnt(0)" ::: "memory");       // publish before count
    __hip_atomic_fetch_add(cnt, 1, __ATOMIC_RELAXED, __HIP_MEMORY_SCOPE_AGENT);
  }

  // ---- U_z (one gate) -> registers, bf16 B-frag order; wave's K-slice only ----
  short8 Uzf[16];
  {
#pragma unroll
    for (int ktl = 0; ktl < 8; ++ktl)
#pragma unroll
      for (int nt = 0; nt < 2; ++nt) {
        const float* src = Uz + (size_t)(j0 + nt * 16 + (lane & 15)) * HH
                         + (w * 8 + ktl) * 32 + (lane >> 4) * 8;
        float4 f0 = ((const float4*)src)[0];
        float4 f1 = ((const float4*)src)[1];
        short8 fr;
        fr[0] = (short)f2bf(f0.x); fr[1] = (short)f2bf(f0.y);
        fr[2] = (short)f2bf(f0.z); fr[3] = (short)f2bf(f0.w);
        fr[4] = (short)f2bf(f1.x); fr[5] = (short)f2bf(f1.y);
        fr[6] = (short)f2bf(f1.z); fr[7] = (short)f2bf(f1.w);
        Uzf[ktl * 2 + nt] = fr;
      }
  }

  // ---- U_r, U_h (fp32) -> LDS bf16 B-frags: 128 chunks (g,kt,nt) / 4 waves ----
  {
    const float* Us2[2] = {Ur, Uh};
    for (int c = w * 32; c < w * 32 + 32; ++c) {
      int g = c >> 6, rem = c & 63, kt = rem >> 1, nt = rem & 1;
      const float* src = Us2[g] + (size_t)(j0 + nt * 16 + (lane & 15)) * HH
                       + kt * 32 + (lane >> 4) * 8;
      float4 f0 = ((const float4*)src)[0];
      float4 f1 = ((const float4*)src)[1];
      short8 fr;
      fr[0] = (short)f2bf(f0.x); fr[1] = (short)f2bf(f0.y);
      fr[2] = (short)f2bf(f0.z); fr[3] = (short)f2bf(f0.w);
      fr[4] = (short)f2bf(f1.x); fr[5] = (short)f2bf(f1.y);
      fr[6] = (short)f2bf(f1.z); fr[7] = (short)f2bf(f1.w);
      *(short8*)(smem + LDS_UF + ((size_t)((g * 32 + kt) * 2 + nt) * 1024) + lane * 16) = fr;
    }
    ((float*)(smem + LDS_HOWN))[tid] = 0.f;   // 8*32 = 256 exact
  }
  __syncthreads();

  // ---- topology check (counter-barrier; works under plain launch too).
  // Result is SUNK (asm sink) — correctness never depends on it this round.
  if (tid == 0) {
    const int* cp = cnt;
    int c;
    do {
      asm volatile("global_load_dword %0, %1, off sc0 sc1\n\t"
                   "s_waitcnt vmcnt(0)" : "=v"(c) : "v"(cp) : "memory");
    } while (c < 256);
    int ok = 1;
    for (int s = 0; s < GBLK; ++s) {
      const int* p = xccOf + group + s * 8;
      int v;
      asm volatile("global_load_dword %0, %1, off sc0 sc1\n\t"
                   "s_waitcnt vmcnt(0)" : "=v"(v) : "v"(p) : "memory");
      ok &= (v == (int)xcc + 1);
    }
    asm volatile("" :: "v"(ok));   // keep alive, unused (rule 17)
  }

  for (int t = 0; t < SS; ++t) {
    // ---- prefetch x-projections (gate = w; rows 0..7 on lanes 0..31) ----
    float xpre[2][4];
    if (w < 3 && lane < 32) {
#pragma unroll
      for (int nt = 0; nt < 2; ++nt)
#pragma unroll
        for (int i = 0; i < 4; ++i) {
          int b = (lane >> 4) * 4 + i;                      // 0..7
          int tok = x[(size_t)(group * GROWS + b) * SS + t];
          xpre[nt][i] = table[(size_t)tok * 3072 + w * 1024 + j0 + nt * 16 + (lane & 15)];
        }
    }

    // ================= phase A : r, z =================
    // Direct register gather of h A-frags (rows duplicated for lanes 8..15;
    // C rows 8..15 are discarded). Plain cached: fresh lines per t, sc1-written.
    short8 ha[8];
    if (t > 0) {
      poll32(myB, t, lane);                                // all waves poll
      const unsigned short* hb = outs + ((size_t)(t - 1) * BB + group * GROWS + (lane & 7)) * HH
                               + w * 256 + (lane >> 4) * 8;
#pragma unroll
      for (int i = 0; i < 8; ++i)
        ha[i] = *(const short8*)(hb + i * 32);
    } else {
      short8 z8 = {0, 0, 0, 0, 0, 0, 0, 0};
#pragma unroll
      for (int i = 0; i < 8; ++i) ha[i] = z8;
    }

    floatx4 ar0 = {0,0,0,0}, ar1 = {0,0,0,0}, az0 = {0,0,0,0}, az1 = {0,0,0,0};
#pragma unroll
    for (int ktl = 0; ktl < 8; ++ktl) {
      const int kt = w * 8 + ktl;
      short8 br0 = *(const short8*)(smem + LDS_UF + (size_t)((kt * 2 + 0) * 1024) + lane * 16);
      short8 br1 = *(const short8*)(smem + LDS_UF + (size_t)((kt * 2 + 1) * 1024) + lane * 16);
      ar0 = __builtin_amdgcn_mfma_f32_16x16x32_bf16(ha[ktl], br0, ar0, 0, 0, 0);
      ar1 = __builtin_amdgcn_mfma_f32_16x16x32_bf16(ha[ktl], br1, ar1, 0, 0, 0);
      az0 = __builtin_amdgcn_mfma_f32_16x16x32_bf16(ha[ktl], Uzf[ktl * 2 + 0], az0, 0, 0, 0);
      az1 = __builtin_amdgcn_mfma_f32_16x16x32_bf16(ha[ktl], Uzf[ktl * 2 + 1], az1, 0, 0, 0);
    }
    *(floatx4*)(redA + ((w * 4 + 0) * 64 + lane) * 4) = ar0;
    *(floatx4*)(redA + ((w * 4 + 1) * 64 + lane) * 4) = ar1;
    *(floatx4*)(redA + ((w * 4 + 2) * 64 + lane) * 4) = az0;
    *(floatx4*)(redA + ((w * 4 + 3) * 64 + lane) * 4) = az1;
    __syncthreads();                                       // B1

    if (w == 0) {        // finalize r; pack r*h; sc1-store handoff; release flagA
      if (lane < 32) {
#pragma unroll
        for (int nt = 0; nt < 2; ++nt) {
          floatx4 s = {0,0,0,0};
#pragma unroll
          for (int ww = 0; ww < 4; ++ww)
            s += *(const floatx4*)(redA + ((ww * 4 + nt) * 64 + lane) * 4);
          const int j = nt * 16 + (lane & 15);
#pragma unroll
          for (int i = 0; i < 4; ++i) {
            int b = (lane >> 4) * 4 + i;                   // 0..7
            float r = 1.f / (1.f + __expf(-(s[i] + xpre[nt][i])));
            xfer[b * 32 + j] = r * h_own[b * 32 + j];
          }
        }
      }
      asm volatile("s_waitcnt lgkmcnt(0)" ::: "memory");   // cross-lane LDS RAW (same wave)
      int row = lane >> 3, c0 = (lane & 7) * 4;
      unsigned long long pk = pack4bf(xfer[row * 32 + c0 + 0], xfer[row * 32 + c0 + 1],
                                      xfer[row * 32 + c0 + 2], xfer[row * 32 + c0 + 3]);
      st_agent_b64((unsigned long long*)(rhbuf + (size_t)(group * GROWS + row) * HH + j0 + c0), pk);
      asm volatile("s_waitcnt vmcnt(0)" ::: "memory");     // data acked before flag
      if (lane == 0)
        __hip_atomic_store(flagsA + group * GBLK + slot, t + 1,
                           __ATOMIC_RELAXED, __HIP_MEMORY_SCOPE_AGENT);
    } else if (w == 1) { // finalize z, keep in LDS
      if (lane < 32) {
#pragma unroll
        for (int nt = 0; nt < 2; ++nt) {
          floatx4 s = {0,0,0,0};
#pragma unroll
          for (int ww = 0; ww < 4; ++ww)
            s += *(const floatx4*)(redA + ((ww * 4 + 2 + nt) * 64 + lane) * 4);
          const int j = nt * 16 + (lane & 15);
#pragma unroll
          for (int i = 0; i < 4; ++i) {
            int b = (lane >> 4) * 4 + i;
            zbuf[b * 32 + j] = 1.f / (1.f + __expf(-(s[i] + xpre[nt][i])));
          }
        }
      }
    }

    // ================= phase B : h_tilde, h_new =================
    poll32(myA, t + 1, lane);                              // all waves poll
    // rh addresses reused every step -> LLC bypass sc0 sc1 (proven protocol).
    short8 rha0, rha1, rha2, rha3, rha4, rha5, rha6, rha7;
    {
      const char* rb = (const char*)(rhbuf + (size_t)(group * GROWS + (lane & 7)) * HH
                                     + w * 256 + (lane >> 4) * 8);
      asm volatile(
        "global_load_dwordx4 %0, %8, off sc0 sc1\n\t"
        "global_load_dwordx4 %1, %8, off offset:64 sc0 sc1\n\t"
        "global_load_dwordx4 %2, %8, off offset:128 sc0 sc1\n\t"
        "global_load_dwordx4 %3, %8, off offset:192 sc0 sc1\n\t"
        "global_load_dwordx4 %4, %8, off offset:256 sc0 sc1\n\t"
        "global_load_dwordx4 %5, %8, off offset:320 sc0 sc1\n\t"
        "global_load_dwordx4 %6, %8, off offset:384 sc0 sc1\n\t"
        "global_load_dwordx4 %7, %8, off offset:448 sc0 sc1\n\t"
        "s_waitcnt vmcnt(0)"
        : "=v"(rha0), "=v"(rha1), "=v"(rha2), "=v"(rha3),
          "=v"(rha4), "=v"(rha5), "=v"(rha6), "=v"(rha7)
        : "v"(rb)
        : "memory");
    }

    floatx4 ah0 = {0,0,0,0}, ah1 = {0,0,0,0};
    {
      short8 rha[8] = {rha0, rha1, rha2, rha3, rha4, rha5, rha6, rha7};
#pragma unroll
      for (int ktl = 0; ktl < 8; ++ktl) {
        const int kt = w * 8 + ktl;
        short8 bh0 = *(const short8*)(smem + LDS_UF + (size_t)(((32 + kt) * 2 + 0) * 1024) + lane * 16);
        short8 bh1 = *(const short8*)(smem + LDS_UF + (size_t)(((32 + kt) * 2 + 1) * 1024) + lane * 16);
        ah0 = __builtin_amdgcn_mfma_f32_16x16x32_bf16(rha[ktl], bh0, ah0, 0, 0, 0);
        ah1 = __builtin_amdgcn_mfma_f32_16x16x32_bf16(rha[ktl], bh1, ah1, 0, 0, 0);
      }
    }
    *(floatx4*)(redB + ((w * 2 + 0) * 64 + lane) * 4) = ah0;
    *(floatx4*)(redB + ((w * 2 + 1) * 64 + lane) * 4) = ah1;
    __syncthreads();                                       // B2

    if (w == 2) {
      if (lane < 32) {
#pragma unroll
        for (int nt = 0; nt < 2; ++nt) {
          floatx4 s = {0,0,0,0};
#pragma unroll
          for (int ww = 0; ww < 4; ++ww)
            s += *(const floatx4*)(redB + ((ww * 2 + nt) * 64 + lane) * 4);
          const int j = nt * 16 + (lane & 15);
#pragma unroll
          for (int i = 0; i < 4; ++i) {
            int b = (lane >> 4) * 4 + i;
            float ht = tanhf(s[i] + xpre[nt][i]);
            float z = zbuf[b * 32 + j];
            float hp = h_own[b * 32 + j];
            h_own[b * 32 + j] = (1.f - z) * ht + z * hp;  // fp32 master copy
          }
        }
      }
      asm volatile("s_waitcnt lgkmcnt(0)" ::: "memory");   // cross-lane LDS RAW (same wave)
      int row = lane >> 3, c0 = (lane & 7) * 4;
      float f0 = h_own[row * 32 + c0 + 0], f1 = h_own[row * 32 + c0 + 1];
      float f2 = h_own[row * 32 + c0 + 2], f3 = h_own[row * 32 + c0 + 3];
      st_agent_b64((unsigned long long*)(outs + (size_t)(t * BB + group * GROWS + row) * HH + j0 + c0),
                   pack4bf(f0, f1, f2, f3));
      if (t == SS - 1) {
        float4 v4 = {f0, f1, f2, f3};
        *(float4*)(hlast + (size_t)(group * GROWS + row) * HH + j0 + c0) = v4;  // fp32, plain
      }
      asm volatile("s_waitcnt vmcnt(0)" ::: "memory");     // data acked before flag
      if (lane == 0)
        __hip_atomic_store(flagsB + group * GBLK + slot, t + 1,
                           __ATOMIC_RELAXED, __HIP_MEMORY_SCOPE_AGENT);
    }
    // no trailing sync: next step's flagsB poll + B1 cover remaining hazards
  }
}

// logits[b][s][v] = outs[s][b][:] . Wfc[v][:] + b_fc[v]   (fp32 out)
__global__ void __launch_bounds__(256)
logits_kernel(const unsigned short* __restrict__ outs, const float* __restrict__ Wfc,
              const float* __restrict__ bfc, float* __restrict__ out) {
  const int lane = threadIdx.x & 63;
  const int mt = blockIdx.x * 4 + (threadIdx.x >> 6);  // M-tile 0..2047 (M = S*B = 32768)
  const size_t arow = (size_t)(mt * 16 + (lane & 15)) * HH + (lane >> 4) * 8;
  floatx4 zero = {0,0,0,0};
  floatx4 acc[8];
#pragma unroll
  for (int n = 0; n < 8; ++n) acc[n] = zero;
  for (int kt = 0; kt < 32; ++kt) {
    short8 a = *(const short8*)(outs + arow + kt * 32);
#pragma unroll
    for (int n = 0; n < 8; ++n) {
      const float* wsrc = Wfc + (size_t)(n * 16 + (lane & 15)) * HH + kt * 32 + (lane >> 4) * 8;
      float4 f0 = ((const float4*)wsrc)[0];
      float4 f1 = ((const float4*)wsrc)[1];
      short8 b;
      b[0] = (short)f2bf(f0.x); b[1] = (short)f2bf(f0.y);
      b[2] = (short)f2bf(f0.z); b[3] = (short)f2bf(f0.w);
      b[4] = (short)f2bf(f1.x); b[5] = (short)f2bf(f1.y);
      b[6] = (short)f2bf(f1.z); b[7] = (short)f2bf(f1.w);
      acc[n] = __builtin_amdgcn_mfma_f32_16x16x32_bf16(a, b, acc[n], 0, 0, 0);
    }
  }
#pragma unroll
  for (int n = 0; n < 8; ++n) {
    int v = n * 16 + (lane & 15);
    float bias = bfc[v];
#pragma unroll
    for (int i = 0; i < 4; ++i) {
      int m = mt * 16 + (lane >> 4) * 4 + i;
      int s = m >> 6, b = m & 63;
      out[((size_t)b * SS + s) * VV + v] = acc[n][i] + bias;
    }
  }
}

extern "C" void kernel_launch(void* const* d_in, const int* in_sizes, int n_in,
                              void* d_out, int out_size, void* d_ws, size_t ws_size,
                              hipStream_t stream) {
  const int*   x    = (const int*)d_in[0];
  const float* emb  = (const float*)d_in[1];
  const float* W_r  = (const float*)d_in[2];
  const float* U_r  = (const float*)d_in[3];
  const float* b_r  = (const float*)d_in[4];
  const float* W_z  = (const float*)d_in[5];
  const float* U_z  = (const float*)d_in[6];
  const float* b_z  = (const float*)d_in[7];
  const float* W_h  = (const float*)d_in[8];
  const float* U_h  = (const float*)d_in[9];
  const float* b_h  = (const float*)d_in[10];
  const float* W_fc = (const float*)d_in[11];
  const float* b_fc = (const float*)d_in[12];

  char* ws = (char*)d_ws;
  float*          table  = (float*)(ws + WS_TABLE);
  unsigned short* rhbuf  = (unsigned short*)(ws + WS_RH);
  int*            flagsA = (int*)(ws + WS_FLAGS);
  int*            flagsB = (int*)(ws + WS_FLAGS + 1024);
  int*            xccOf  = (int*)(ws + WS_FLAGS + 2048);
  int*            cnt    = (int*)(ws + WS_FLAGS + 3072);
  unsigned short* outs   = (unsigned short*)(ws + WS_OUTS);
  float*          out    = (float*)d_out;
  float*          hlast  = out + (size_t)BB * SS * VV;   // output 1, fp32

  // flags/xcc/cnt must start at 0 every call (ws is re-poisoned to 0xAA)
  hipMemsetAsync(ws + WS_FLAGS, 0, 4096, stream);

  table_kernel<<<dim3((128 * 3 * 1024) / 256), dim3(256), 0, stream>>>(
      emb, W_r, b_r, W_z, b_z, W_h, b_h, table);

  hipFuncSetAttribute(reinterpret_cast<const void*>(gru_kernel),
                      hipFuncAttributeMaxDynamicSharedMemorySize, LDS_ALLOC);
  void* args[] = {(void*)&x, (void*)&U_r, (void*)&U_z, (void*)&U_h, (void*)&table,
                  (void*)&outs, (void*)&rhbuf, (void*)&hlast,
                  (void*)&flagsA, (void*)&flagsB, (void*)&xccOf, (void*)&cnt};
  hipError_t cerr = hipLaunchCooperativeKernel(reinterpret_cast<void*>(gru_kernel),
                                               dim3(256), dim3(256),
                                               args, (unsigned)LDS_ALLOC, stream);
  if (cerr != hipSuccess) {
    // Fallback: plain launch. No grid.sync() anywhere; 1-block/CU LDS forcing
    // makes all 256 blocks co-resident, which the flag protocol requires.
    // (R7 lesson: unchecked cooperative-launch rejection = silent no-op.)
    gru_kernel<<<dim3(256), dim3(256), LDS_ALLOC, stream>>>(
        x, U_r, U_z, U_h, table, outs, rhbuf, hlast, flagsA, flagsB, xccOf, cnt);
  }

  logits_kernel<<<dim3(512), dim3(256), 0, stream>>>(outs, W_fc, b_fc, out);
}